// Round 12
// baseline (124.699 us; speedup 1.0000x reference)
//
#include <hip/hip_runtime.h>
#include <hip/hip_bf16.h>
#include <math.h>

// Problem constants: B=256, V=2048, PD=1024, MD=512, H=512
typedef __attribute__((ext_vector_type(8))) short short8;
typedef __attribute__((ext_vector_type(4))) float float4v;
typedef __attribute__((ext_vector_type(2))) float float2v;

// SSA-safe half extraction (NO unions -- unions block SROA and spill).
__device__ __forceinline__ float2v lo2(float4v v) {
    return __builtin_shufflevector(v, v, 0, 1);
}
__device__ __forceinline__ float2v hi2(float4v v) {
    return __builtin_shufflevector(v, v, 2, 3);
}

__device__ __forceinline__ int2 cvt2bf16x4(float4v v) {
    union { __hip_bfloat162 h2; int i; } u0, u1;
    u0.h2 = __float22bfloat162_rn(make_float2(v.x, v.y));  // v_cvt_pk_bf16_f32
    u1.h2 = __float22bfloat162_rn(make_float2(v.z, v.w));
    return make_int2(u0.i, u1.i);
}

// Fused dual GEMM + exp epilogue (plain [h][x] layout, contiguous stores).
//  bx 0..1:  EA[h][b] = exp(2*(patient@W1p^T + b1))   M=256,  K=1024
//  bx 2..17: EM[h][v] = exp(2*(atc4@W1m^T))           M=2048, K=512
// Round 12 = round 11 resubmitted verbatim (round 11 was an infra failure,
// not a kernel verdict): (a) 128x64 tiles -> 144 blocks, <=1 block/CU:
// kills the 1.125-blocks/CU tail (32 CUs previously ran 2 serial blocks);
// EA blocks (2x k-iters, the critical path) launch first. (b) true LDS
// double-buffer, ONE barrier per k-iter: loads for tile k+1 issue BEFORE
// the MFMA phase of tile k and their waitcnt lands after it -- the ~600cy
// global latency hides under compute instead of being exposed 8-16x/block.
// NOTE (round-3 lesson): do NOT fuse cross-block reductions with
// __threadfence on this chip -- agent-scope fences flush per-XCD L2.
__global__ __launch_bounds__(256, 1) void gemm_exp(
    const float* __restrict__ patient, const float* __restrict__ atc4,
    const float* __restrict__ W1, const float* __restrict__ b1,
    float* __restrict__ EA, float* __restrict__ EM)
{
    const float* A; const float* W; const float* bias; float* T;
    int lda, K, M;
    int bx = blockIdx.x;
    if (bx < 2) {
        A = patient; lda = 1024; K = 1024; M = 256; bias = b1; T = EA; W = W1;
    } else {
        bx -= 2;
        A = atc4;    lda = 512;  K = 512;  M = 2048; bias = nullptr; T = EM; W = W1 + 1024;
    }
    const int ldw = 1536;

    __shared__ short As[2][128][72];   // 36.9 KB
    __shared__ short Bs[2][64][72];    // 18.4 KB  (total 55.3 KB)
    const int t = threadIdx.x;
    const int m0 = bx * 128;
    const int n0 = blockIdx.y * 64;
    const int wave = t >> 6;
    const int lane = t & 63;
    const int wm = (wave & 1) * 64;    // m-half of the 128-row tile
    const int wn = (wave >> 1) * 32;   // n-half of the 64-col tile
    const int lrow = lane & 15;
    const int quad = lane >> 4;

    float4v acc[4][2];
    #pragma unroll
    for (int i = 0; i < 4; i++)
        #pragma unroll
        for (int j = 0; j < 2; j++)
            acc[i][j] = (float4v){0.f, 0.f, 0.f, 0.f};

    // A staging: 128 rows x 64 cols -> 2 threads/row, 32 floats each
    const int sa_r = t >> 1;           // 0..127
    const int sa_c = (t & 1) * 32;     // 0 or 32
    // B staging: 64 rows x 64 cols -> 4 threads/row, 16 floats each
    const int sb_r = t >> 2;           // 0..63
    const int sb_c = (t & 3) * 16;     // 0,16,32,48

    float4v av[8], wv[4];
    // ---- prologue: load + stage k-tile 0 into buf 0 ----
    {
        const float* ap = A + (size_t)(m0 + sa_r) * lda + sa_c;
        #pragma unroll
        for (int ii = 0; ii < 8; ii++) av[ii] = *(const float4v*)(ap + ii * 4);
        const float* wp = W + (size_t)(n0 + sb_r) * ldw + sb_c;
        #pragma unroll
        for (int ii = 0; ii < 4; ii++) wv[ii] = *(const float4v*)(wp + ii * 4);
        #pragma unroll
        for (int ii = 0; ii < 8; ii++)
            *(int2*)&As[0][sa_r][sa_c + ii * 4] = cvt2bf16x4(av[ii]);
        #pragma unroll
        for (int ii = 0; ii < 4; ii++)
            *(int2*)&Bs[0][sb_r][sb_c + ii * 4] = cvt2bf16x4(wv[ii]);
    }
    __syncthreads();

    int cur = 0;
    for (int k0 = 0; k0 < K; k0 += 64) {
        const bool has_next = (k0 + 64 < K);
        if (has_next) {   // issue next-tile loads; waitcnt lands after MFMA
            const float* ap = A + (size_t)(m0 + sa_r) * lda + (k0 + 64 + sa_c);
            #pragma unroll
            for (int ii = 0; ii < 8; ii++) av[ii] = *(const float4v*)(ap + ii * 4);
            const float* wp = W + (size_t)(n0 + sb_r) * ldw + (k0 + 64 + sb_c);
            #pragma unroll
            for (int ii = 0; ii < 4; ii++) wv[ii] = *(const float4v*)(wp + ii * 4);
        }
        #pragma unroll
        for (int kk = 0; kk < 64; kk += 32) {
            short8 af[4], bfr[2];
            #pragma unroll
            for (int i = 0; i < 4; i++)
                af[i] = *(const short8*)&As[cur][wm + i * 16 + lrow][kk + quad * 8];
            #pragma unroll
            for (int j = 0; j < 2; j++)
                bfr[j] = *(const short8*)&Bs[cur][wn + j * 16 + lrow][kk + quad * 8];
            #pragma unroll
            for (int i = 0; i < 4; i++)
                #pragma unroll
                for (int j = 0; j < 2; j++)
                    acc[i][j] = __builtin_amdgcn_mfma_f32_16x16x32_bf16(
                        af[i], bfr[j], acc[i][j], 0, 0, 0);
        }
        if (has_next) {
            const int nxt = cur ^ 1;
            #pragma unroll
            for (int ii = 0; ii < 8; ii++)
                *(int2*)&As[nxt][sa_r][sa_c + ii * 4] = cvt2bf16x4(av[ii]);
            #pragma unroll
            for (int ii = 0; ii < 4; ii++)
                *(int2*)&Bs[nxt][sb_r][sb_c + ii * 4] = cvt2bf16x4(wv[ii]);
            __syncthreads();   // buf[nxt] staged; everyone done reading buf[cur]
            cur = nxt;
        }
    }

    // D layout (verified m89/m91): col(n)=lane&15, row(m)=quad*4+reg
    #pragma unroll
    for (int i = 0; i < 4; i++) {
        #pragma unroll
        for (int j = 0; j < 2; j++) {
            const int n  = n0 + wn + j * 16 + lrow;
            const int mb = m0 + wm + i * 16 + quad * 4;
            const float bn = bias ? bias[n] : 0.0f;
            float4v ev;
            #pragma unroll
            for (int r = 0; r < 4; r++)
                ev[r] = __expf(2.0f * (acc[i][j][r] + bn));
            *(float4v*)&T[(size_t)n * M + mb] = ev;
        }
    }
}

// 4-h rational block: acc += sum_{k=0..3} c_k / d_k, d_k = 1 + em_k*a_k.
//   (n01*e23 + n23*e01)/(e01*e23); all d >= 1 so no cancellation.
__device__ __forceinline__ void rat4(
    float2v em0, float2v em1, float2v em2, float2v em3,
    float2v a0, float2v a1, float2v a2, float2v a3,
    float2v c0, float2v c1, float2v c2, float2v c3,
    float2v& acc)
{
    const float2v one2 = {1.f, 1.f};
    float2v d0 = __builtin_elementwise_fma(em0, a0, one2);
    float2v d1 = __builtin_elementwise_fma(em1, a1, one2);
    float2v d2 = __builtin_elementwise_fma(em2, a2, one2);
    float2v d3 = __builtin_elementwise_fma(em3, a3, one2);
    float2v e01 = d0 * d1;
    float2v e23 = d2 * d3;
    float2v n01 = __builtin_elementwise_fma(d1, c0, d0 * c1);
    float2v n23 = __builtin_elementwise_fma(d3, c2, d2 * c3);
    float2v num = __builtin_elementwise_fma(n01, e23, n23 * e01);
    float2v den = e01 * e23;
    float2v r = { __builtin_amdgcn_rcpf(den.x), __builtin_amdgcn_rcpf(den.y) };
    acc = __builtin_elementwise_fma(num, r, acc);
}

// partial[z][b][v] = sum_{h in 64-chunk z} [ w2[h] + c_h / d_h ],
//   c = -2*w2, d = 1 + Ea[h][b]*Em[h][v]    (w2*tanh(x) = w2 - 2*w2/(1+e^{2x}))
// R8 form FROZEN (best measured total 110.55): 4v x 4b threads, 64h blocks
// staged once, grid (32,4,8). Pair has been invariant ~37 us across
// occupancy 1-6 blk/CU, pipelining, pressure, and encoding variants --
// this round leaves it untouched while gemm is rebuilt (attribution).
__global__ __launch_bounds__(256, 4) void pair_kernel(
    const float* __restrict__ EA, const float* __restrict__ EM,
    const float* __restrict__ w2, float* __restrict__ partial)
{
    __shared__ float sEA[64][68];    // [h][b], 64 cols used
    __shared__ float sEM[64][68];    // [h][v], 64 cols used
    __shared__ float4v sC4[16];      // -2*w2 quads for the 64-h chunk
    const int t  = threadIdx.x;
    const int v0 = blockIdx.x * 64;
    const int b0 = blockIdx.y * 64;
    const int h0 = blockIdx.z * 64;
    const int tx = t & 15;   // v = v0 + tx*4 + j
    const int ty = t >> 4;   // b = b0 + ty*4 + i

    if (t < 16) {
        float4v wvq = *(const float4v*)(w2 + h0 + 4 * t);
        sC4[t] = -2.0f * wvq;
    }

    float2v accL[4], accH[4];        // [b][low/high half of v-quad]
    #pragma unroll
    for (int i = 0; i < 4; i++) {
        accL[i] = (float2v){0.f, 0.f};
        accH[i] = (float2v){0.f, 0.f};
    }

    // ---- stage the block's 64-h chunk (once): 4 threads/row, 4 float4 each
    {
        const int rS = t >> 2;            // row 0..63
        const int c0i = (t & 3) * 16;     // col 0,16,32,48
        const float* pa = EA + (size_t)(h0 + rS) * 256 + b0 + c0i;
        const float* pm = EM + (size_t)(h0 + rS) * 2048 + v0 + c0i;
        #pragma unroll
        for (int i = 0; i < 4; i++) {
            float4v va = *(const float4v*)(pa + 4 * i);
            float4v vm = *(const float4v*)(pm + 4 * i);
            *(float4v*)&sEA[rS][c0i + 4 * i] = va;
            *(float4v*)&sEM[rS][c0i + 4 * i] = vm;
        }
    }
    __syncthreads();

    #pragma unroll 1
    for (int q = 0; q < 16; q++) {       // 4 h per iteration, minimal live set
        const int hq = 4 * q;
        const float4v m0 = *(const float4v*)&sEM[hq    ][tx * 4];
        const float4v m1 = *(const float4v*)&sEM[hq + 1][tx * 4];
        const float4v m2 = *(const float4v*)&sEM[hq + 2][tx * 4];
        const float4v m3 = *(const float4v*)&sEM[hq + 3][tx * 4];
        const float4v ea0 = *(const float4v*)&sEA[hq    ][ty * 4];
        const float4v ea1 = *(const float4v*)&sEA[hq + 1][ty * 4];
        const float4v ea2 = *(const float4v*)&sEA[hq + 2][ty * 4];
        const float4v ea3 = *(const float4v*)&sEA[hq + 3][ty * 4];
        const float4v c = sC4[q];
        const float2v c0 = { c.x, c.x };
        const float2v c1 = { c.y, c.y };
        const float2v c2 = { c.z, c.z };
        const float2v c3 = { c.w, c.w };
        const float2v m0L = lo2(m0), m0H = hi2(m0);
        const float2v m1L = lo2(m1), m1H = hi2(m1);
        const float2v m2L = lo2(m2), m2H = hi2(m2);
        const float2v m3L = lo2(m3), m3H = hi2(m3);
        #pragma unroll
        for (int i = 0; i < 4; i++) {    // b within the thread's 4
            const float2v a0 = { ea0[i], ea0[i] };
            const float2v a1 = { ea1[i], ea1[i] };
            const float2v a2 = { ea2[i], ea2[i] };
            const float2v a3 = { ea3[i], ea3[i] };
            rat4(m0L, m1L, m2L, m3L, a0, a1, a2, a3, c0, c1, c2, c3, accL[i]);
            rat4(m0H, m1H, m2H, m3H, a0, a1, a2, a3, c0, c1, c2, c3, accH[i]);
        }
    }

    // chunk's sum(w2) from sC4 (sC4 = -2*w2)
    float4v w2q = sC4[0];
    #pragma unroll
    for (int k = 1; k < 16; k++) w2q += sC4[k];
    const float w2s = -0.5f * (w2q.x + w2q.y + w2q.z + w2q.w);

    const size_t pb = (size_t)blockIdx.z * (256 * 2048);
    #pragma unroll
    for (int i = 0; i < 4; i++) {
        const size_t row = pb + (size_t)(b0 + ty * 4 + i) * 2048 + v0 + tx * 4;
        float4v o = { accL[i].x + w2s, accL[i].y + w2s,
                      accH[i].x + w2s, accH[i].y + w2s };
        *(float4v*)&partial[row] = o;
    }
}

__global__ __launch_bounds__(256) void reduce_kernel(
    const float* __restrict__ partial, const float* __restrict__ b2,
    float* __restrict__ out)
{
    const int i = (blockIdx.x * 256 + threadIdx.x) * 4;
    const float bb = b2[0];
    float4v s = *(const float4v*)&partial[i];
    #pragma unroll
    for (int z = 1; z < 8; z++)
        s += *(const float4v*)&partial[(size_t)z * 524288 + i];
    float4v o = s + bb;
    *(float4v*)&out[i] = o;
}

extern "C" void kernel_launch(void* const* d_in, const int* in_sizes, int n_in,
                              void* d_out, int out_size, void* d_ws, size_t ws_size,
                              hipStream_t stream)
{
    const float* patient = (const float*)d_in[0]; // 256x1024
    const float* atc4    = (const float*)d_in[1]; // 2048x512
    const float* W1      = (const float*)d_in[2]; // 512x1536
    const float* b1      = (const float*)d_in[3]; // 512
    const float* w2      = (const float*)d_in[4]; // 512
    const float* b2      = (const float*)d_in[5]; // 1
    float* out = (float*)d_out;
    float* ws  = (float*)d_ws;

    // ws layout (floats): EA[512][256], EM[512][2048],
    //                     partial[8][256][2048] => ~21.5 MB
    float* EA      = ws;
    float* EM      = ws + 131072;
    float* partial = ws + 1179648;

    // Dual GEMM, 128x64 tiles (144 blocks, no tail), LDS double-buffered
    gemm_exp<<<dim3(18, 8, 1), 256, 0, stream>>>(patient, atc4, W1, b1, EA, EM);
    // score partials: R8 form (frozen)
    pair_kernel<<<dim3(32, 4, 8), 256, 0, stream>>>(EA, EM, w2, partial);
    // sum 8 h-chunks + b2
    reduce_kernel<<<512, 256, 0, stream>>>(partial, b2, out);
}

// Round 13
// 111.115 us; speedup vs baseline: 1.1223x; 1.1223x over previous
//
#include <hip/hip_runtime.h>
#include <hip/hip_bf16.h>
#include <math.h>

// Problem constants: B=256, V=2048, PD=1024, MD=512, H=512
typedef __attribute__((ext_vector_type(8))) short short8;
typedef __attribute__((ext_vector_type(4))) float float4v;
typedef __attribute__((ext_vector_type(2))) float float2v;

// SSA-safe half extraction (NO unions -- unions block SROA and spill).
__device__ __forceinline__ float2v lo2(float4v v) {
    return __builtin_shufflevector(v, v, 0, 1);
}
__device__ __forceinline__ float2v hi2(float4v v) {
    return __builtin_shufflevector(v, v, 2, 3);
}

__device__ __forceinline__ int2 cvt2bf16x4(float4v v) {
    union { __hip_bfloat162 h2; int i; } u0, u1;
    u0.h2 = __float22bfloat162_rn(make_float2(v.x, v.y));  // v_cvt_pk_bf16_f32
    u1.h2 = __float22bfloat162_rn(make_float2(v.z, v.w));
    return make_int2(u0.i, u1.i);
}

// Fused dual GEMM + exp epilogue (plain [h][x] layout, contiguous stores).
//  bx 0..3:  EA[h][b] = exp(2*(patient@W1p^T + b1))   M=256,  K=1024
//  bx 4..35: EM[h][v] = exp(2*(atc4@W1m^T))           M=2048, K=512
// R8 form (best measured total 110.55): 64x64 tiles, grid (36,8) = 288
// blocks (full CU coverage; EA tiles first so the K=1024 critical path
// starts immediately), register prefetch of the next k-tile.
// Round-12 lesson: 128x64 tiles (144 blocks) idle 44% of CUs -> +14 us.
// NOTE (round-3 lesson): do NOT fuse cross-block reductions with
// __threadfence on this chip -- agent-scope fences flush per-XCD L2 and
// cost ~30 us. Separate dispatches keep workspace traffic L2-hot.
__global__ __launch_bounds__(256, 2) void gemm_exp(
    const float* __restrict__ patient, const float* __restrict__ atc4,
    const float* __restrict__ W1, const float* __restrict__ b1,
    float* __restrict__ EA, float* __restrict__ EM)
{
    const float* A; const float* W; const float* bias; float* T;
    int lda, K, M;
    int bx = blockIdx.x;
    if (bx < 4) {
        A = patient; lda = 1024; K = 1024; M = 256; bias = b1; T = EA; W = W1;
    } else {
        bx -= 4;
        A = atc4;    lda = 512;  K = 512;  M = 2048; bias = nullptr; T = EM; W = W1 + 1024;
    }
    const int ldw = 1536;

    __shared__ short As[64][72];
    __shared__ short Bs[64][72];
    const int t = threadIdx.x;
    const int m0 = bx * 64;
    const int n0 = blockIdx.y * 64;
    const int wave = t >> 6;
    const int lane = t & 63;
    const int wm = (wave & 1) * 32;
    const int wn = (wave >> 1) * 32;
    const int lrow = lane & 15;
    const int quad = lane >> 4;

    float4v acc[2][2];
    #pragma unroll
    for (int i = 0; i < 2; i++)
        #pragma unroll
        for (int j = 0; j < 2; j++)
            acc[i][j] = (float4v){0.f, 0.f, 0.f, 0.f};

    const int sr = t >> 2;        // staging row 0..63
    const int sc = (t & 3) * 16;  // staging col 0,16,32,48

    // preload k-tile 0 into registers
    float4v av[4], wv[4];
    {
        const float* ap = A + (size_t)(m0 + sr) * lda + sc;
        const float* wp = W + (size_t)(n0 + sr) * ldw + sc;
        #pragma unroll
        for (int ii = 0; ii < 4; ii++) {
            av[ii] = *(const float4v*)(ap + ii * 4);
            wv[ii] = *(const float4v*)(wp + ii * 4);
        }
    }

    for (int k0 = 0; k0 < K; k0 += 64) {
        #pragma unroll
        for (int ii = 0; ii < 4; ii++) {
            *(int2*)&As[sr][sc + ii * 4] = cvt2bf16x4(av[ii]);
            *(int2*)&Bs[sr][sc + ii * 4] = cvt2bf16x4(wv[ii]);
        }
        __syncthreads();
        if (k0 + 64 < K) {   // prefetch next k-tile; latency hides under MFMA
            const float* ap = A + (size_t)(m0 + sr) * lda + (k0 + 64 + sc);
            const float* wp = W + (size_t)(n0 + sr) * ldw + (k0 + 64 + sc);
            #pragma unroll
            for (int ii = 0; ii < 4; ii++) {
                av[ii] = *(const float4v*)(ap + ii * 4);
                wv[ii] = *(const float4v*)(wp + ii * 4);
            }
        }
        #pragma unroll
        for (int kk = 0; kk < 64; kk += 32) {
            short8 af[2], bfr[2];
            #pragma unroll
            for (int i = 0; i < 2; i++)
                af[i] = *(const short8*)&As[wm + i * 16 + lrow][kk + quad * 8];
            #pragma unroll
            for (int j = 0; j < 2; j++)
                bfr[j] = *(const short8*)&Bs[wn + j * 16 + lrow][kk + quad * 8];
            #pragma unroll
            for (int i = 0; i < 2; i++)
                #pragma unroll
                for (int j = 0; j < 2; j++)
                    acc[i][j] = __builtin_amdgcn_mfma_f32_16x16x32_bf16(
                        af[i], bfr[j], acc[i][j], 0, 0, 0);
        }
        __syncthreads();
    }

    // D layout (verified m89/m91): col(n)=lane&15, row(m)=quad*4+reg
    #pragma unroll
    for (int i = 0; i < 2; i++) {
        #pragma unroll
        for (int j = 0; j < 2; j++) {
            const int n  = n0 + wn + j * 16 + lrow;
            const int mb = m0 + wm + i * 16 + quad * 4;
            const float bn = bias ? bias[n] : 0.0f;
            float4v ev;
            #pragma unroll
            for (int r = 0; r < 4; r++)
                ev[r] = __expf(2.0f * (acc[i][j][r] + bn));
            *(float4v*)&T[(size_t)n * M + mb] = ev;
        }
    }
}

// 4-h rational block: acc += sum_{k=0..3} c_k / d_k, d_k = 1 + em_k*a_k.
//   (n01*e23 + n23*e01)/(e01*e23); all d >= 1 so no cancellation.
__device__ __forceinline__ void rat4(
    float2v em0, float2v em1, float2v em2, float2v em3,
    float2v a0, float2v a1, float2v a2, float2v a3,
    float2v c0, float2v c1, float2v c2, float2v c3,
    float2v& acc)
{
    const float2v one2 = {1.f, 1.f};
    float2v d0 = __builtin_elementwise_fma(em0, a0, one2);
    float2v d1 = __builtin_elementwise_fma(em1, a1, one2);
    float2v d2 = __builtin_elementwise_fma(em2, a2, one2);
    float2v d3 = __builtin_elementwise_fma(em3, a3, one2);
    float2v e01 = d0 * d1;
    float2v e23 = d2 * d3;
    float2v n01 = __builtin_elementwise_fma(d1, c0, d0 * c1);
    float2v n23 = __builtin_elementwise_fma(d3, c2, d2 * c3);
    float2v num = __builtin_elementwise_fma(n01, e23, n23 * e01);
    float2v den = e01 * e23;
    float2v r = { __builtin_amdgcn_rcpf(den.x), __builtin_amdgcn_rcpf(den.y) };
    acc = __builtin_elementwise_fma(num, r, acc);
}

// partial[z][b][v] = sum_{h in 64-chunk z} [ w2[h] + c_h / d_h ],
//   c = -2*w2, d = 1 + Ea[h][b]*Em[h][v]    (w2*tanh(x) = w2 - 2*w2/(1+e^{2x}))
// R8 form FROZEN (best measured total 110.55): 4v x 4b threads, 64h blocks
// staged once, grid (32,4,8) = 4 blocks/CU. Pair measured invariant
// (~37-38 us) across occupancy 1-6 blk/CU, pipelining, VGPR caps,
// working-set size, and float2/float4 encoding -- all falsified levers.
__global__ __launch_bounds__(256, 4) void pair_kernel(
    const float* __restrict__ EA, const float* __restrict__ EM,
    const float* __restrict__ w2, float* __restrict__ partial)
{
    __shared__ float sEA[64][68];    // [h][b], 64 cols used
    __shared__ float sEM[64][68];    // [h][v], 64 cols used
    __shared__ float4v sC4[16];      // -2*w2 quads for the 64-h chunk
    const int t  = threadIdx.x;
    const int v0 = blockIdx.x * 64;
    const int b0 = blockIdx.y * 64;
    const int h0 = blockIdx.z * 64;
    const int tx = t & 15;   // v = v0 + tx*4 + j
    const int ty = t >> 4;   // b = b0 + ty*4 + i

    if (t < 16) {
        float4v wvq = *(const float4v*)(w2 + h0 + 4 * t);
        sC4[t] = -2.0f * wvq;
    }

    float2v accL[4], accH[4];        // [b][low/high half of v-quad]
    #pragma unroll
    for (int i = 0; i < 4; i++) {
        accL[i] = (float2v){0.f, 0.f};
        accH[i] = (float2v){0.f, 0.f};
    }

    // ---- stage the block's 64-h chunk (once): 4 threads/row, 4 float4 each
    {
        const int rS = t >> 2;            // row 0..63
        const int c0i = (t & 3) * 16;     // col 0,16,32,48
        const float* pa = EA + (size_t)(h0 + rS) * 256 + b0 + c0i;
        const float* pm = EM + (size_t)(h0 + rS) * 2048 + v0 + c0i;
        #pragma unroll
        for (int i = 0; i < 4; i++) {
            float4v va = *(const float4v*)(pa + 4 * i);
            float4v vm = *(const float4v*)(pm + 4 * i);
            *(float4v*)&sEA[rS][c0i + 4 * i] = va;
            *(float4v*)&sEM[rS][c0i + 4 * i] = vm;
        }
    }
    __syncthreads();

    #pragma unroll 1
    for (int q = 0; q < 16; q++) {       // 4 h per iteration, minimal live set
        const int hq = 4 * q;
        const float4v m0 = *(const float4v*)&sEM[hq    ][tx * 4];
        const float4v m1 = *(const float4v*)&sEM[hq + 1][tx * 4];
        const float4v m2 = *(const float4v*)&sEM[hq + 2][tx * 4];
        const float4v m3 = *(const float4v*)&sEM[hq + 3][tx * 4];
        const float4v ea0 = *(const float4v*)&sEA[hq    ][ty * 4];
        const float4v ea1 = *(const float4v*)&sEA[hq + 1][ty * 4];
        const float4v ea2 = *(const float4v*)&sEA[hq + 2][ty * 4];
        const float4v ea3 = *(const float4v*)&sEA[hq + 3][ty * 4];
        const float4v c = sC4[q];
        const float2v c0 = { c.x, c.x };
        const float2v c1 = { c.y, c.y };
        const float2v c2 = { c.z, c.z };
        const float2v c3 = { c.w, c.w };
        const float2v m0L = lo2(m0), m0H = hi2(m0);
        const float2v m1L = lo2(m1), m1H = hi2(m1);
        const float2v m2L = lo2(m2), m2H = hi2(m2);
        const float2v m3L = lo2(m3), m3H = hi2(m3);
        #pragma unroll
        for (int i = 0; i < 4; i++) {    // b within the thread's 4
            const float2v a0 = { ea0[i], ea0[i] };
            const float2v a1 = { ea1[i], ea1[i] };
            const float2v a2 = { ea2[i], ea2[i] };
            const float2v a3 = { ea3[i], ea3[i] };
            rat4(m0L, m1L, m2L, m3L, a0, a1, a2, a3, c0, c1, c2, c3, accL[i]);
            rat4(m0H, m1H, m2H, m3H, a0, a1, a2, a3, c0, c1, c2, c3, accH[i]);
        }
    }

    // chunk's sum(w2) from sC4 (sC4 = -2*w2)
    float4v w2q = sC4[0];
    #pragma unroll
    for (int k = 1; k < 16; k++) w2q += sC4[k];
    const float w2s = -0.5f * (w2q.x + w2q.y + w2q.z + w2q.w);

    const size_t pb = (size_t)blockIdx.z * (256 * 2048);
    #pragma unroll
    for (int i = 0; i < 4; i++) {
        const size_t row = pb + (size_t)(b0 + ty * 4 + i) * 2048 + v0 + tx * 4;
        float4v o = { accL[i].x + w2s, accL[i].y + w2s,
                      accH[i].x + w2s, accH[i].y + w2s };
        *(float4v*)&partial[row] = o;
    }
}

__global__ __launch_bounds__(256) void reduce_kernel(
    const float* __restrict__ partial, const float* __restrict__ b2,
    float* __restrict__ out)
{
    const int i = (blockIdx.x * 256 + threadIdx.x) * 4;
    const float bb = b2[0];
    float4v s = *(const float4v*)&partial[i];
    #pragma unroll
    for (int z = 1; z < 8; z++)
        s += *(const float4v*)&partial[(size_t)z * 524288 + i];
    float4v o = s + bb;
    *(float4v*)&out[i] = o;
}

extern "C" void kernel_launch(void* const* d_in, const int* in_sizes, int n_in,
                              void* d_out, int out_size, void* d_ws, size_t ws_size,
                              hipStream_t stream)
{
    const float* patient = (const float*)d_in[0]; // 256x1024
    const float* atc4    = (const float*)d_in[1]; // 2048x512
    const float* W1      = (const float*)d_in[2]; // 512x1536
    const float* b1      = (const float*)d_in[3]; // 512
    const float* w2      = (const float*)d_in[4]; // 512
    const float* b2      = (const float*)d_in[5]; // 1
    float* out = (float*)d_out;
    float* ws  = (float*)d_ws;

    // ws layout (floats): EA[512][256], EM[512][2048],
    //                     partial[8][256][2048] => ~21.5 MB
    float* EA      = ws;
    float* EM      = ws + 131072;
    float* partial = ws + 1179648;

    // Both GEMMs in one dispatch (compacted grid, EA tiles first); exp(2x) epilogue
    gemm_exp<<<dim3(36, 8, 1), 256, 0, stream>>>(patient, atc4, W1, b1, EA, EM);
    // score partials: minimal-pressure 4v x 4b threads, 64h blocks, 4 blk/CU
    pair_kernel<<<dim3(32, 4, 8), 256, 0, stream>>>(EA, EM, w2, partial);
    // sum 8 h-chunks + b2
    reduce_kernel<<<512, 256, 0, stream>>>(partial, b2, out);
}